// Round 1
// baseline (239.064 us; speedup 1.0000x reference)
//
#include <hip/hip_runtime.h>

// LIF forward recurrence:
//   mem0 = x[0]; spike0 = (mem0 > 0.5)
//   mem_t = mem_{t-1} * 0.25 * (1 - spike_{t-1}) + x_t ; spike_t = (mem_t > 0.5)
// Output: spikes [T, B, D] float32.
//
// Round 2 measured 81 µs/dispatch, 2.48 TB/s (31% peak), VALUBusy 3.8%,
// VGPR=32 — the declared bufA/bufB double-buffer (needs >=64 VGPRs) was
// sunk by the compiler back to load-at-use, leaving ~2 loads in flight on
// a serial dependency chain, at grid-limited 16 waves/CU.
//
// Round 3: (a) asm memory-clobber fences after each prefetch group make
// sinking illegal -> buffers stay live, 8-16 loads in flight per thread;
// (b) float2 work items double the grid to 2048 blocks -> 8 blocks/CU ->
// 32 waves/CU (full TLP). __launch_bounds__(256,8) caps VGPR at 64 so
// occupancy holds (buffers now cost 32 VGPRs, fits).

constexpr int   T_STEPS = 32;
constexpr int   CHUNK   = 8;
constexpr float THRESH  = 0.5f;
constexpr float DECAY   = 0.25f;

typedef float v2f __attribute__((ext_vector_type(2)));

// Compiler + MachineScheduler barrier for memory ops: loads issued above
// this line cannot be sunk below it (and thus must be materialized early).
#define PIPELINE_FENCE() asm volatile("" ::: "memory")

__device__ __forceinline__ void load_chunk(float2* buf, const float2* __restrict__ xp,
                                           int t0, int n2) {
#pragma unroll
    for (int k = 0; k < CHUNK; ++k)
        buf[k] = xp[(size_t)(t0 + k) * (size_t)n2];
}

template <int T0>
__device__ __forceinline__ void compute_chunk(const float2* buf, float2& mem, float2& s,
                                              float2* __restrict__ op, int n2) {
#pragma unroll
    for (int k = 0; k < CHUNK; ++k) {
        float2 v = buf[k];
        if (T0 + k == 0) {
            mem = v;  // mem0 = x[0]
        } else {
            mem.x = mem.x * (DECAY * (1.0f - s.x)) + v.x;
            mem.y = mem.y * (DECAY * (1.0f - s.y)) + v.y;
        }
        s.x = mem.x > THRESH ? 1.0f : 0.0f;
        s.y = mem.y > THRESH ? 1.0f : 0.0f;
        v2f sv = {s.x, s.y};
        __builtin_nontemporal_store(sv, (v2f*)(op + (size_t)(T0 + k) * (size_t)n2));
    }
}

__global__ __launch_bounds__(256, 8) void lif_fwd_kernel(
    const float2* __restrict__ x,   // [T, n2]
    float2* __restrict__ out,       // [T, n2]
    int n2)
{
    int i = blockIdx.x * 256 + threadIdx.x;
    if (i >= n2) return;

    const float2* xp = x + i;
    float2*       op = out + i;

    float2 bufA[CHUNK], bufB[CHUNK];
    float2 mem, s;

    // Pipeline: A(0-7) and B(8-15) in flight; fence; compute A while
    // prefetching A(16-23); fence; compute B while prefetching B(24-31);
    // fence; compute A; compute B.
    load_chunk(bufA, xp, 0, n2);
    load_chunk(bufB, xp, 8, n2);
    PIPELINE_FENCE();

    compute_chunk<0>(bufA, mem, s, op, n2);
    load_chunk(bufA, xp, 16, n2);
    PIPELINE_FENCE();

    compute_chunk<8>(bufB, mem, s, op, n2);
    load_chunk(bufB, xp, 24, n2);
    PIPELINE_FENCE();

    compute_chunk<16>(bufA, mem, s, op, n2);
    compute_chunk<24>(bufB, mem, s, op, n2);
}

extern "C" void kernel_launch(void* const* d_in, const int* in_sizes, int n_in,
                              void* d_out, int out_size, void* d_ws, size_t ws_size,
                              hipStream_t stream) {
    const float* x = (const float*)d_in[0];
    float* out = (float*)d_out;

    const int total = in_sizes[0];        // T * B * D = 33_554_432
    const int n     = total / T_STEPS;    // B * D     = 1_048_576
    const int n2    = n / 2;              // 524_288 float2 work items

    const int block = 256;
    const int grid  = (n2 + block - 1) / block;  // 2048 blocks -> 8/CU -> 32 waves/CU

    lif_fwd_kernel<<<grid, block, 0, stream>>>(
        reinterpret_cast<const float2*>(x),
        reinterpret_cast<float2*>(out),
        n2);
}